// Round 7
// baseline (732.760 us; speedup 1.0000x reference)
//
#include <hip/hip_runtime.h>

// ConvCaps EM-routing, MI355X. 392 problems, one 1024-thread block each.
// Thread = (o = t&31, kc = t>>5 of 32 chunks, 9 k each). Fused E+M (3 vote passes).
// R7: 8 waves/SIMD on loaded CUs (1024-thr blocks, VGPR<=64 via launch_bounds);
// cross-chunk reduction via LDS fp32 atomics (ds_add_f32) into a 32x33 accumulator
// (double-buffered, zeroed one pass ahead) — no scr matrix, no bpermute combines.
// P rows staged in LDS (broadcast ds_read_b128); softmax via DPP butterflies.

namespace {

constexpr int NKK = 288;
constexpr float EPSF = 1e-8f;
constexpr float LN2PI = 1.8378770664093453f;

typedef float v2f __attribute__((ext_vector_type(2)));

__device__ __forceinline__ float fastrcp(float x) { return __builtin_amdgcn_rcpf(x); }

template <int CTRL>
__device__ __forceinline__ float dppf(float v) {
    return __builtin_bit_cast(float,
        __builtin_amdgcn_update_dpp(0, __builtin_bit_cast(int, v), CTRL, 0xF, 0xF, true));
}
__device__ __forceinline__ float swz16(float v) {   // xor 16 within 32-lane halves
    return __builtin_bit_cast(float,
        __builtin_amdgcn_ds_swizzle(__builtin_bit_cast(int, v), 0x401F));
}
__device__ __forceinline__ float rmax32(float v) {
    v = fmaxf(v, dppf<0xB1>(v));    // xor 1
    v = fmaxf(v, dppf<0x4E>(v));    // xor 2
    v = fmaxf(v, dppf<0x141>(v));   // xor 7 (row_half_mirror)
    v = fmaxf(v, dppf<0x140>(v));   // xor 15 (row_mirror)
    v = fmaxf(v, swz16(v));         // xor 16
    return v;
}
__device__ __forceinline__ float rsum32(float v) {
    v += dppf<0xB1>(v); v += dppf<0x4E>(v);
    v += dppf<0x141>(v); v += dppf<0x140>(v);
    v += swz16(v);
    return v;
}
__device__ __forceinline__ float rsum16(float v) {  // over p (lanes&15)
    v += dppf<0xB1>(v); v += dppf<0x4E>(v);
    v += dppf<0x141>(v); v += dppf<0x140>(v);
    return v;
}

__global__ __launch_bounds__(1024, 8)
void caps_em_kernel(const float* __restrict__ x,
                    const float* __restrict__ Wg,
                    const float* __restrict__ bu,
                    const float* __restrict__ ba,
                    float* __restrict__ out)
{
    // LDS: 18432 + 1152 + 8448 + 2304 + 2304 + 128 + 128 = 32896 B
    __shared__ float p4[NKK * 16];       // pose fragments [k*16+p]
    __shared__ float cIn[NKK];           // a/(a+eps)
    __shared__ float acc[2][32 * 33];    // [buf][o*33 + (Sv 0..15 | Sq 16..31 | S0 32)]
    __shared__ float meanS[32 * 18];
    __shared__ float i2vS[32 * 18];
    __shared__ float actS[32];
    __shared__ float baseS[32];

    const int n = blockIdx.x;
    const int t = threadIdx.x;

    // ---- gather poses: flat view of tiled (B,kh,kw,oh,ow,512) ----
    for (int idx = t; idx < NKK * 16; idx += 1024) {
        unsigned g = (unsigned)n * 4608u + (unsigned)idx;
        unsigned c = g & 511u, rest = g >> 9;
        unsigned ow = rest % 7u; rest /= 7u;
        unsigned oh = rest % 7u; rest /= 7u;
        unsigned kw = rest % 3u; rest /= 3u;
        unsigned kh = rest % 3u;
        unsigned b  = rest / 3u;
        p4[idx] = x[((b*16u + 2u*oh + kh)*16u + 2u*ow + kw)*544u + c];
    }
    // ---- gather acts -> c_k ----
    for (int idx = t; idx < NKK; idx += 1024) {
        unsigned g = (unsigned)n * 288u + (unsigned)idx;
        unsigned c = g & 31u, rest = g >> 5;
        unsigned ow = rest % 7u; rest /= 7u;
        unsigned oh = rest % 7u; rest /= 7u;
        unsigned kw = rest % 3u; rest /= 3u;
        unsigned kh = rest % 3u;
        unsigned b  = rest / 3u;
        const float a = x[((b*16u + 2u*oh + kh)*16u + 2u*ow + kw)*544u + 512u + c];
        cIn[idx] = a / (a + EPSF);
    }
    if (t < 1056 - 1024) { }             // (no-op; sizes below handled by loops)
    for (int idx = t; idx < 32 * 33; idx += 1024) { acc[0][idx] = 0.f; acc[1][idx] = 0.f; }
    __syncthreads();

    const int o  = t & 31;    // out-cap (== lane&31)
    const int kc = t >> 5;    // k-chunk 0..31 (9 k each)

    float lam = 1.0e-3f;

    for (int it = 0; it < 3; ++it) {
        lam += 1.0e-4f;

        // zero the buffer pass it+1 will accumulate into (safe: its last reader
        // finished before the final barrier of pass it-1)
        float* aznext = acc[(it + 1) & 1];
        for (int idx = t; idx < 32 * 33; idx += 1024) aznext[idx] = 0.f;

        float S0 = 0.f;
        v2f Sv[8], Sq[8];
        #pragma unroll
        for (int q = 0; q < 8; ++q) { Sv[q] = (v2f)(0.f); Sq[q] = (v2f)(0.f); }

        if (it == 0) {
            // ---- M0: uniform r -> u_k = c_k/32 ----
            #pragma unroll 3
            for (int kk = 0; kk < 9; ++kk) {
                const int k = kc*9 + kk;
                const float w = cIn[k] * 0.03125f;
                float P[16]; v2f W2[8];
                #pragma unroll
                for (int j = 0; j < 4; ++j) {
                    const float4 v4 = *(const float4*)&p4[k*16 + j*4];
                    P[j*4] = v4.x; P[j*4+1] = v4.y; P[j*4+2] = v4.z; P[j*4+3] = v4.w;
                    const float4 w4 = *(const float4*)&Wg[(unsigned)k*512u + (unsigned)o*16u + j*4];
                    W2[j*2]   = (v2f){w4.x, w4.y};
                    W2[j*2+1] = (v2f){w4.z, w4.w};
                }
                S0 += w;
                #pragma unroll
                for (int i = 0; i < 4; ++i) {
                    #pragma unroll
                    for (int m2 = 0; m2 < 2; ++m2) {
                        v2f v = P[i*4] * W2[m2];
                        v += P[i*4+1] * W2[2+m2];
                        v += P[i*4+2] * W2[4+m2];
                        v += P[i*4+3] * W2[6+m2];
                        const v2f wv = v * w;
                        Sv[i*2+m2] += wv;
                        Sq[i*2+m2] += wv * v;
                    }
                }
            }
        } else {
            // ---- fused E(prev stats) + M accumulate ----
            v2f M2[8], I2[8];
            #pragma unroll
            for (int q = 0; q < 8; ++q) {
                M2[q] = *(const v2f*)&meanS[o*18 + q*2];
                I2[q] = *(const v2f*)&i2vS [o*18 + q*2];
            }
            const float base = baseS[o];
            #pragma unroll 3
            for (int kk = 0; kk < 9; ++kk) {
                const int k = kc*9 + kk;
                float P[16]; v2f W2[8];
                #pragma unroll
                for (int j = 0; j < 4; ++j) {
                    const float4 v4 = *(const float4*)&p4[k*16 + j*4];
                    P[j*4] = v4.x; P[j*4+1] = v4.y; P[j*4+2] = v4.z; P[j*4+3] = v4.w;
                    const float4 w4 = *(const float4*)&Wg[(unsigned)k*512u + (unsigned)o*16u + j*4];
                    W2[j*2]   = (v2f){w4.x, w4.y};
                    W2[j*2+1] = (v2f){w4.z, w4.w};
                }
                v2f vt[8];
                v2f sacc2 = (v2f)(0.f);
                #pragma unroll
                for (int i = 0; i < 4; ++i) {
                    #pragma unroll
                    for (int m2 = 0; m2 < 2; ++m2) {
                        v2f v = P[i*4] * W2[m2];
                        v += P[i*4+1] * W2[2+m2];
                        v += P[i*4+2] * W2[4+m2];
                        v += P[i*4+3] * W2[6+m2];
                        vt[i*2+m2] = v;
                        const v2f d = v - M2[i*2+m2];
                        sacc2 += (d * I2[i*2+m2]) * d;
                    }
                }
                const float lnp = base - (sacc2.x + sacc2.y);
                const float mx = rmax32(lnp);
                const float e  = __expf(lnp - mx);
                const float ss = rsum32(e);
                const float u  = e * fastrcp(ss) * cIn[k];
                S0 += u;
                #pragma unroll
                for (int q = 0; q < 8; ++q) {
                    const v2f uv = vt[q] * u;
                    Sv[q] += uv;
                    Sq[q] += uv * vt[q];
                }
            }
        }

        // ---- cross-chunk reduction: LDS fp32 atomics (lane l and l^32 share
        // the same address -> 2-way same-address aliasing, free per HW) ----
        {
            float* ac = acc[it & 1];
            #pragma unroll
            for (int q = 0; q < 8; ++q) {
                atomicAdd(&ac[o*33 + 2*q],        Sv[q].x);
                atomicAdd(&ac[o*33 + 2*q + 1],    Sv[q].y);
                atomicAdd(&ac[o*33 + 16 + 2*q],   Sq[q].x);
                atomicAdd(&ac[o*33 + 16 + 2*q+1], Sq[q].y);
            }
            atomicAdd(&ac[o*33 + 32], S0);
        }
        __syncthreads();

        // ---- stats + activation; threads t<512 = (oo, pp) ----
        if (t < 512) {
            const int oo = t >> 4, pp = t & 15;
            const float* ac = acc[it & 1];
            const float sm = ac[oo*33 + pp];
            const float s2 = ac[oo*33 + 16 + pp];
            const float rs = ac[oo*33 + 32];
            const float inv = 1.0f / (rs + EPSF);
            const float S1  = rs * inv;
            const float m   = sm * inv;
            float var = s2 * inv - m*m*(2.0f - S1);
            var = fmaxf(var, 0.0f) + EPSF;          // std^2 (+eps inside sqrt)
            meanS[oo*18 + pp] = m;
            i2vS [oo*18 + pp] = 0.5f / var;
            const float ls = rsum16(0.5f * __logf(var));
            if (pp == 0) {
                const float cost = (16.0f * bu[oo] + ls) * rs;
                const float ao   = 1.0f / (1.0f + __expf(-lam * (ba[oo] - cost)));
                actS[oo]  = ao;
                baseS[oo] = -ls - 8.0f*LN2PI + __logf(ao);
            }
        }
        __syncthreads();
    }

    // ---- output: [mean(512) | act(32)] per n ----
    if (t < 544) {
        const float v = (t < 512) ? meanS[(t >> 4)*18 + (t & 15)]
                                  : actS[t - 512];
        out[n*544 + t] = v;
    }
}

} // namespace

extern "C" void kernel_launch(void* const* d_in, const int* in_sizes, int n_in,
                              void* d_out, int out_size, void* d_ws, size_t ws_size,
                              hipStream_t stream) {
    (void)in_sizes; (void)n_in; (void)out_size; (void)d_ws; (void)ws_size;
    const float* x  = (const float*)d_in[0];
    const float* W  = (const float*)d_in[1];
    const float* bu = (const float*)d_in[2];
    const float* ba = (const float*)d_in[3];
    float* out = (float*)d_out;
    caps_em_kernel<<<dim3(392), dim3(1024), 0, stream>>>(x, W, bu, ba, out);
}

// Round 8
// 382.678 us; speedup vs baseline: 1.9148x; 1.9148x over previous
//
#include <hip/hip_runtime.h>

// ConvCaps EM-routing, MI355X. 392 problems, one 1024-thread block each.
// Thread = (o = t&31, kc = t>>5 of 32 chunks, 9 k each). Fused E+M (3 vote passes).
// R8: identical to R7 but __launch_bounds__(1024, 4) — R7's (1024,8) forced a
// 32-VGPR cap and spilled all per-thread arrays to scratch (hbm 2 GB, 696 us).
// Cap 128 lets the allocator use ~64 VGPR (as in R4-R6); HW still fits 2 blocks/CU.

namespace {

constexpr int NKK = 288;
constexpr float EPSF = 1e-8f;
constexpr float LN2PI = 1.8378770664093453f;

typedef float v2f __attribute__((ext_vector_type(2)));

__device__ __forceinline__ float fastrcp(float x) { return __builtin_amdgcn_rcpf(x); }

template <int CTRL>
__device__ __forceinline__ float dppf(float v) {
    return __builtin_bit_cast(float,
        __builtin_amdgcn_update_dpp(0, __builtin_bit_cast(int, v), CTRL, 0xF, 0xF, true));
}
__device__ __forceinline__ float swz16(float v) {   // xor 16 within 32-lane halves
    return __builtin_bit_cast(float,
        __builtin_amdgcn_ds_swizzle(__builtin_bit_cast(int, v), 0x401F));
}
__device__ __forceinline__ float rmax32(float v) {
    v = fmaxf(v, dppf<0xB1>(v));    // xor 1
    v = fmaxf(v, dppf<0x4E>(v));    // xor 2
    v = fmaxf(v, dppf<0x141>(v));   // xor 7 (row_half_mirror)
    v = fmaxf(v, dppf<0x140>(v));   // xor 15 (row_mirror)
    v = fmaxf(v, swz16(v));         // xor 16
    return v;
}
__device__ __forceinline__ float rsum32(float v) {
    v += dppf<0xB1>(v); v += dppf<0x4E>(v);
    v += dppf<0x141>(v); v += dppf<0x140>(v);
    v += swz16(v);
    return v;
}
__device__ __forceinline__ float rsum16(float v) {  // over p (lanes&15)
    v += dppf<0xB1>(v); v += dppf<0x4E>(v);
    v += dppf<0x141>(v); v += dppf<0x140>(v);
    return v;
}

__global__ __launch_bounds__(1024, 4)
void caps_em_kernel(const float* __restrict__ x,
                    const float* __restrict__ Wg,
                    const float* __restrict__ bu,
                    const float* __restrict__ ba,
                    float* __restrict__ out)
{
    // LDS: 18432 + 1152 + 8448 + 2304 + 2304 + 128 + 128 = 32896 B
    __shared__ float p4[NKK * 16];       // pose fragments [k*16+p]
    __shared__ float cIn[NKK];           // a/(a+eps)
    __shared__ float acc[2][32 * 33];    // [buf][o*33 + (Sv 0..15 | Sq 16..31 | S0 32)]
    __shared__ float meanS[32 * 18];
    __shared__ float i2vS[32 * 18];
    __shared__ float actS[32];
    __shared__ float baseS[32];

    const int n = blockIdx.x;
    const int t = threadIdx.x;

    // ---- gather poses: flat view of tiled (B,kh,kw,oh,ow,512) ----
    for (int idx = t; idx < NKK * 16; idx += 1024) {
        unsigned g = (unsigned)n * 4608u + (unsigned)idx;
        unsigned c = g & 511u, rest = g >> 9;
        unsigned ow = rest % 7u; rest /= 7u;
        unsigned oh = rest % 7u; rest /= 7u;
        unsigned kw = rest % 3u; rest /= 3u;
        unsigned kh = rest % 3u;
        unsigned b  = rest / 3u;
        p4[idx] = x[((b*16u + 2u*oh + kh)*16u + 2u*ow + kw)*544u + c];
    }
    // ---- gather acts -> c_k ----
    for (int idx = t; idx < NKK; idx += 1024) {
        unsigned g = (unsigned)n * 288u + (unsigned)idx;
        unsigned c = g & 31u, rest = g >> 5;
        unsigned ow = rest % 7u; rest /= 7u;
        unsigned oh = rest % 7u; rest /= 7u;
        unsigned kw = rest % 3u; rest /= 3u;
        unsigned kh = rest % 3u;
        unsigned b  = rest / 3u;
        const float a = x[((b*16u + 2u*oh + kh)*16u + 2u*ow + kw)*544u + 512u + c];
        cIn[idx] = a / (a + EPSF);
    }
    for (int idx = t; idx < 32 * 33; idx += 1024) { acc[0][idx] = 0.f; acc[1][idx] = 0.f; }
    __syncthreads();

    const int o  = t & 31;    // out-cap (== lane&31)
    const int kc = t >> 5;    // k-chunk 0..31 (9 k each)

    float lam = 1.0e-3f;

    for (int it = 0; it < 3; ++it) {
        lam += 1.0e-4f;

        // zero the buffer pass it+1 will accumulate into
        float* aznext = acc[(it + 1) & 1];
        for (int idx = t; idx < 32 * 33; idx += 1024) aznext[idx] = 0.f;

        float S0 = 0.f;
        v2f Sv[8], Sq[8];
        #pragma unroll
        for (int q = 0; q < 8; ++q) { Sv[q] = (v2f)(0.f); Sq[q] = (v2f)(0.f); }

        if (it == 0) {
            // ---- M0: uniform r -> u_k = c_k/32 ----
            #pragma unroll 3
            for (int kk = 0; kk < 9; ++kk) {
                const int k = kc*9 + kk;
                const float w = cIn[k] * 0.03125f;
                float P[16]; v2f W2[8];
                #pragma unroll
                for (int j = 0; j < 4; ++j) {
                    const float4 v4 = *(const float4*)&p4[k*16 + j*4];
                    P[j*4] = v4.x; P[j*4+1] = v4.y; P[j*4+2] = v4.z; P[j*4+3] = v4.w;
                    const float4 w4 = *(const float4*)&Wg[(unsigned)k*512u + (unsigned)o*16u + j*4];
                    W2[j*2]   = (v2f){w4.x, w4.y};
                    W2[j*2+1] = (v2f){w4.z, w4.w};
                }
                S0 += w;
                #pragma unroll
                for (int i = 0; i < 4; ++i) {
                    #pragma unroll
                    for (int m2 = 0; m2 < 2; ++m2) {
                        v2f v = P[i*4] * W2[m2];
                        v += P[i*4+1] * W2[2+m2];
                        v += P[i*4+2] * W2[4+m2];
                        v += P[i*4+3] * W2[6+m2];
                        const v2f wv = v * w;
                        Sv[i*2+m2] += wv;
                        Sq[i*2+m2] += wv * v;
                    }
                }
            }
        } else {
            // ---- fused E(prev stats) + M accumulate ----
            v2f M2[8], I2[8];
            #pragma unroll
            for (int q = 0; q < 8; ++q) {
                M2[q] = *(const v2f*)&meanS[o*18 + q*2];
                I2[q] = *(const v2f*)&i2vS [o*18 + q*2];
            }
            const float base = baseS[o];
            #pragma unroll 3
            for (int kk = 0; kk < 9; ++kk) {
                const int k = kc*9 + kk;
                float P[16]; v2f W2[8];
                #pragma unroll
                for (int j = 0; j < 4; ++j) {
                    const float4 v4 = *(const float4*)&p4[k*16 + j*4];
                    P[j*4] = v4.x; P[j*4+1] = v4.y; P[j*4+2] = v4.z; P[j*4+3] = v4.w;
                    const float4 w4 = *(const float4*)&Wg[(unsigned)k*512u + (unsigned)o*16u + j*4];
                    W2[j*2]   = (v2f){w4.x, w4.y};
                    W2[j*2+1] = (v2f){w4.z, w4.w};
                }
                v2f vt[8];
                v2f sacc2 = (v2f)(0.f);
                #pragma unroll
                for (int i = 0; i < 4; ++i) {
                    #pragma unroll
                    for (int m2 = 0; m2 < 2; ++m2) {
                        v2f v = P[i*4] * W2[m2];
                        v += P[i*4+1] * W2[2+m2];
                        v += P[i*4+2] * W2[4+m2];
                        v += P[i*4+3] * W2[6+m2];
                        vt[i*2+m2] = v;
                        const v2f d = v - M2[i*2+m2];
                        sacc2 += (d * I2[i*2+m2]) * d;
                    }
                }
                const float lnp = base - (sacc2.x + sacc2.y);
                const float mx = rmax32(lnp);
                const float e  = __expf(lnp - mx);
                const float ss = rsum32(e);
                const float u  = e * fastrcp(ss) * cIn[k];
                S0 += u;
                #pragma unroll
                for (int q = 0; q < 8; ++q) {
                    const v2f uv = vt[q] * u;
                    Sv[q] += uv;
                    Sq[q] += uv * vt[q];
                }
            }
        }

        // ---- cross-chunk reduction: LDS fp32 atomics (lane l and l^32 hit the
        // same address -> 2-way same-address aliasing, free per HW model) ----
        {
            float* ac = acc[it & 1];
            #pragma unroll
            for (int q = 0; q < 8; ++q) {
                atomicAdd(&ac[o*33 + 2*q],        Sv[q].x);
                atomicAdd(&ac[o*33 + 2*q + 1],    Sv[q].y);
                atomicAdd(&ac[o*33 + 16 + 2*q],   Sq[q].x);
                atomicAdd(&ac[o*33 + 16 + 2*q+1], Sq[q].y);
            }
            atomicAdd(&ac[o*33 + 32], S0);
        }
        __syncthreads();

        // ---- stats + activation; threads t<512 = (oo, pp) ----
        if (t < 512) {
            const int oo = t >> 4, pp = t & 15;
            const float* ac = acc[it & 1];
            const float sm = ac[oo*33 + pp];
            const float s2 = ac[oo*33 + 16 + pp];
            const float rs = ac[oo*33 + 32];
            const float inv = 1.0f / (rs + EPSF);
            const float S1  = rs * inv;
            const float m   = sm * inv;
            float var = s2 * inv - m*m*(2.0f - S1);
            var = fmaxf(var, 0.0f) + EPSF;          // std^2 (+eps inside sqrt)
            meanS[oo*18 + pp] = m;
            i2vS [oo*18 + pp] = 0.5f / var;
            const float ls = rsum16(0.5f * __logf(var));
            if (pp == 0) {
                const float cost = (16.0f * bu[oo] + ls) * rs;
                const float ao   = 1.0f / (1.0f + __expf(-lam * (ba[oo] - cost)));
                actS[oo]  = ao;
                baseS[oo] = -ls - 8.0f*LN2PI + __logf(ao);
            }
        }
        __syncthreads();
    }

    // ---- output: [mean(512) | act(32)] per n ----
    if (t < 544) {
        const float v = (t < 512) ? meanS[(t >> 4)*18 + (t & 15)]
                                  : actS[t - 512];
        out[n*544 + t] = v;
    }
}

} // namespace

extern "C" void kernel_launch(void* const* d_in, const int* in_sizes, int n_in,
                              void* d_out, int out_size, void* d_ws, size_t ws_size,
                              hipStream_t stream) {
    (void)in_sizes; (void)n_in; (void)out_size; (void)d_ws; (void)ws_size;
    const float* x  = (const float*)d_in[0];
    const float* W  = (const float*)d_in[1];
    const float* bu = (const float*)d_in[2];
    const float* ba = (const float*)d_in[3];
    float* out = (float*)d_out;
    caps_em_kernel<<<dim3(392), dim3(1024), 0, stream>>>(x, W, bu, ba, out);
}

// Round 9
// 140.624 us; speedup vs baseline: 5.2108x; 2.7213x over previous
//
#include <hip/hip_runtime.h>

// ConvCaps EM-routing, MI355X. 392 problems, one 1024-thread block each.
// Thread = (o = t&31, kc = t>>5 of 32 chunks, 9 k each). Fused E+M (3 vote passes).
// R9: R8's 1024-thread shape (64 VGPR, no spills) with the reduction done as a
// two-stage scr-matrix tree (shfl_xor(32) pair-combine -> 16 groups -> stride-17
// LDS rows -> 512 readers), NOT LDS atomics (R8: 32-way same-address ds_add_f32
// serialized, 338us). Softmax via DPP butterflies + one ds_swizzle (xor16).

namespace {

constexpr int NKK = 288;
constexpr float EPSF = 1e-8f;
constexpr float LN2PI = 1.8378770664093453f;

typedef float v2f __attribute__((ext_vector_type(2)));

__device__ __forceinline__ float fastrcp(float x) { return __builtin_amdgcn_rcpf(x); }

template <int CTRL>
__device__ __forceinline__ float dppf(float v) {
    return __builtin_bit_cast(float,
        __builtin_amdgcn_update_dpp(0, __builtin_bit_cast(int, v), CTRL, 0xF, 0xF, true));
}
__device__ __forceinline__ float swz16(float v) {   // xor 16 within 32-lane halves
    return __builtin_bit_cast(float,
        __builtin_amdgcn_ds_swizzle(__builtin_bit_cast(int, v), 0x401F));
}
__device__ __forceinline__ float rmax32(float v) {
    v = fmaxf(v, dppf<0xB1>(v));    // xor 1
    v = fmaxf(v, dppf<0x4E>(v));    // xor 2
    v = fmaxf(v, dppf<0x141>(v));   // xor 7 (row_half_mirror)
    v = fmaxf(v, dppf<0x140>(v));   // xor 15 (row_mirror)
    v = fmaxf(v, swz16(v));         // xor 16
    return v;
}
__device__ __forceinline__ float rsum32(float v) {
    v += dppf<0xB1>(v); v += dppf<0x4E>(v);
    v += dppf<0x141>(v); v += dppf<0x140>(v);
    v += swz16(v);
    return v;
}
__device__ __forceinline__ float rsum16(float v) {  // over p (lanes&15)
    v += dppf<0xB1>(v); v += dppf<0x4E>(v);
    v += dppf<0x141>(v); v += dppf<0x140>(v);
    return v;
}

__global__ __launch_bounds__(1024, 4)
void caps_em_kernel(const float* __restrict__ x,
                    const float* __restrict__ Wg,
                    const float* __restrict__ bu,
                    const float* __restrict__ ba,
                    float* __restrict__ out)
{
    // LDS: 18432 + 1152 + 34816 + 2304 + 2304 + 128 + 128 = 59264 B -> 2 blocks/CU
    __shared__ float p4[NKK * 16];       // pose fragments [k*16+p]
    __shared__ float cIn[NKK];           // a/(a+eps)
    __shared__ float scr[16 * 32 * 17];  // [g][o][ 16 vals | extra ]
    __shared__ float meanS[32 * 18];
    __shared__ float i2vS[32 * 18];
    __shared__ float actS[32];
    __shared__ float baseS[32];

    const int n = blockIdx.x;
    const int t = threadIdx.x;

    // ---- gather poses: flat view of tiled (B,kh,kw,oh,ow,512) ----
    for (int idx = t; idx < NKK * 16; idx += 1024) {
        unsigned g = (unsigned)n * 4608u + (unsigned)idx;
        unsigned c = g & 511u, rest = g >> 9;
        unsigned ow = rest % 7u; rest /= 7u;
        unsigned oh = rest % 7u; rest /= 7u;
        unsigned kw = rest % 3u; rest /= 3u;
        unsigned kh = rest % 3u;
        unsigned b  = rest / 3u;
        p4[idx] = x[((b*16u + 2u*oh + kh)*16u + 2u*ow + kw)*544u + c];
    }
    // ---- gather acts -> c_k ----
    for (int idx = t; idx < NKK; idx += 1024) {
        unsigned g = (unsigned)n * 288u + (unsigned)idx;
        unsigned c = g & 31u, rest = g >> 5;
        unsigned ow = rest % 7u; rest /= 7u;
        unsigned oh = rest % 7u; rest /= 7u;
        unsigned kw = rest % 3u; rest /= 3u;
        unsigned kh = rest % 3u;
        unsigned b  = rest / 3u;
        const float a = x[((b*16u + 2u*oh + kh)*16u + 2u*ow + kw)*544u + 512u + c];
        cIn[idx] = a / (a + EPSF);
    }
    __syncthreads();

    const int o  = t & 31;    // out-cap (== lane&31)
    const int kc = t >> 5;    // k-chunk 0..31 (9 k each)
    const int oo = t >> 4;    // stats row (t<512)
    const int pp = t & 15;    // stats col

    float lam = 1.0e-3f;

    for (int it = 0; it < 3; ++it) {
        lam += 1.0e-4f;

        float S0 = 0.f;
        v2f Sv[8], Sq[8];
        #pragma unroll
        for (int q = 0; q < 8; ++q) { Sv[q] = (v2f)(0.f); Sq[q] = (v2f)(0.f); }

        if (it == 0) {
            // ---- M0: uniform r -> u_k = c_k/32 ----
            #pragma unroll 3
            for (int kk = 0; kk < 9; ++kk) {
                const int k = kc*9 + kk;
                const float w = cIn[k] * 0.03125f;
                float P[16]; v2f W2[8];
                #pragma unroll
                for (int j = 0; j < 4; ++j) {
                    const float4 v4 = *(const float4*)&p4[k*16 + j*4];
                    P[j*4] = v4.x; P[j*4+1] = v4.y; P[j*4+2] = v4.z; P[j*4+3] = v4.w;
                    const float4 w4 = *(const float4*)&Wg[(unsigned)k*512u + (unsigned)o*16u + j*4];
                    W2[j*2]   = (v2f){w4.x, w4.y};
                    W2[j*2+1] = (v2f){w4.z, w4.w};
                }
                S0 += w;
                #pragma unroll
                for (int i = 0; i < 4; ++i) {
                    #pragma unroll
                    for (int m2 = 0; m2 < 2; ++m2) {
                        v2f v = P[i*4] * W2[m2];
                        v += P[i*4+1] * W2[2+m2];
                        v += P[i*4+2] * W2[4+m2];
                        v += P[i*4+3] * W2[6+m2];
                        const v2f wv = v * w;
                        Sv[i*2+m2] += wv;
                        Sq[i*2+m2] += wv * v;
                    }
                }
            }
        } else {
            // ---- fused E(prev stats) + M accumulate ----
            v2f M2[8], I2[8];
            #pragma unroll
            for (int q = 0; q < 8; ++q) {
                M2[q] = *(const v2f*)&meanS[o*18 + q*2];
                I2[q] = *(const v2f*)&i2vS [o*18 + q*2];
            }
            const float base = baseS[o];
            #pragma unroll 3
            for (int kk = 0; kk < 9; ++kk) {
                const int k = kc*9 + kk;
                float P[16]; v2f W2[8];
                #pragma unroll
                for (int j = 0; j < 4; ++j) {
                    const float4 v4 = *(const float4*)&p4[k*16 + j*4];
                    P[j*4] = v4.x; P[j*4+1] = v4.y; P[j*4+2] = v4.z; P[j*4+3] = v4.w;
                    const float4 w4 = *(const float4*)&Wg[(unsigned)k*512u + (unsigned)o*16u + j*4];
                    W2[j*2]   = (v2f){w4.x, w4.y};
                    W2[j*2+1] = (v2f){w4.z, w4.w};
                }
                v2f vt[8];
                v2f sacc2 = (v2f)(0.f);
                #pragma unroll
                for (int i = 0; i < 4; ++i) {
                    #pragma unroll
                    for (int m2 = 0; m2 < 2; ++m2) {
                        v2f v = P[i*4] * W2[m2];
                        v += P[i*4+1] * W2[2+m2];
                        v += P[i*4+2] * W2[4+m2];
                        v += P[i*4+3] * W2[6+m2];
                        vt[i*2+m2] = v;
                        const v2f d = v - M2[i*2+m2];
                        sacc2 += (d * I2[i*2+m2]) * d;
                    }
                }
                const float lnp = base - (sacc2.x + sacc2.y);
                const float mx = rmax32(lnp);
                const float e  = __expf(lnp - mx);
                const float ss = rsum32(e);
                const float u  = e * fastrcp(ss) * cIn[k];
                S0 += u;
                #pragma unroll
                for (int q = 0; q < 8; ++q) {
                    const v2f uv = vt[q] * u;
                    Sv[q] += uv;
                    Sq[q] += uv * vt[q];
                }
            }
        }

        // ---- pair-combine (kc, kc^1 live in one wave) -> 16 groups ----
        S0 += __shfl_xor(S0, 32, 64);
        #pragma unroll
        for (int q = 0; q < 8; ++q) {
            Sv[q].x += __shfl_xor(Sv[q].x, 32, 64);
            Sv[q].y += __shfl_xor(Sv[q].y, 32, 64);
            Sq[q].x += __shfl_xor(Sq[q].x, 32, 64);
            Sq[q].y += __shfl_xor(Sq[q].y, 32, 64);
        }

        // ---- stage A: Sv + S0 ----
        if ((kc & 1) == 0) {
            float* row = &scr[((kc >> 1)*32 + o)*17];
            #pragma unroll
            for (int q = 0; q < 8; ++q) { row[2*q] = Sv[q].x; row[2*q+1] = Sv[q].y; }
            row[16] = S0;
        }
        __syncthreads();
        float sm = 0.f, rs = 0.f, inv = 0.f, m = 0.f;
        if (t < 512) {
            #pragma unroll
            for (int q = 0; q < 16; ++q) {
                sm += scr[(q*32 + oo)*17 + pp];
                rs += scr[(q*32 + oo)*17 + 16];
            }
            inv = 1.0f / (rs + EPSF);
            m   = sm * inv;
            meanS[oo*18 + pp] = m;
        }
        __syncthreads();

        // ---- stage B: Sq ----
        if ((kc & 1) == 0) {
            float* row = &scr[((kc >> 1)*32 + o)*17];
            #pragma unroll
            for (int q = 0; q < 8; ++q) { row[2*q] = Sq[q].x; row[2*q+1] = Sq[q].y; }
        }
        __syncthreads();
        if (t < 512) {
            float s2 = 0.f;
            #pragma unroll
            for (int q = 0; q < 16; ++q) s2 += scr[(q*32 + oo)*17 + pp];
            const float S1 = rs * inv;
            float var = s2 * inv - m*m*(2.0f - S1);
            var = fmaxf(var, 0.0f) + EPSF;          // std^2 (+eps inside sqrt)
            i2vS[oo*18 + pp] = 0.5f / var;
            const float ls = rsum16(0.5f * __logf(var));
            if (pp == 0) {
                const float cost = (16.0f * bu[oo] + ls) * rs;
                const float ao   = 1.0f / (1.0f + __expf(-lam * (ba[oo] - cost)));
                actS[oo]  = ao;
                baseS[oo] = -ls - 8.0f*LN2PI + __logf(ao);
            }
        }
        __syncthreads();
    }

    // ---- output: [mean(512) | act(32)] per n ----
    if (t < 544) {
        const float v = (t < 512) ? meanS[(t >> 4)*18 + (t & 15)]
                                  : actS[t - 512];
        out[n*544 + t] = v;
    }
}

} // namespace

extern "C" void kernel_launch(void* const* d_in, const int* in_sizes, int n_in,
                              void* d_out, int out_size, void* d_ws, size_t ws_size,
                              hipStream_t stream) {
    (void)in_sizes; (void)n_in; (void)out_size; (void)d_ws; (void)ws_size;
    const float* x  = (const float*)d_in[0];
    const float* W  = (const float*)d_in[1];
    const float* bu = (const float*)d_in[2];
    const float* ba = (const float*)d_in[3];
    float* out = (float*)d_out;
    caps_em_kernel<<<dim3(392), dim3(1024), 0, stream>>>(x, W, bu, ba, out);
}